// Round 5
// baseline (1084.977 us; speedup 1.0000x reference)
//
#include <hip/hip_runtime.h>

#define LATENT 128
#define EF 16
#define NN 50000

// ---------------- f16 helpers --------------------------------------------
typedef _Float16 h2_t __attribute__((ext_vector_type(2)));

#if defined(__has_builtin)
#if __has_builtin(__builtin_amdgcn_fdot2)
#define HAVE_FDOT2 1
#endif
#endif

__device__ inline h2_t as_h2(unsigned u) {
    union { unsigned u; h2_t h; } x; x.u = u; return x.h;
}
__device__ inline float fdot2f(h2_t a, h2_t b, float c) {
#ifdef HAVE_FDOT2
    return __builtin_amdgcn_fdot2(a, b, c, false);
#else
    c = fmaf((float)a.x, (float)b.x, c);
    return fmaf((float)a.y, (float)b.y, c);
#endif
}
__device__ inline unsigned packh2(float a, float b) {
    union { h2_t h; unsigned u; } x;
    x.h.x = (_Float16)a; x.h.y = (_Float16)b; return x.u;
}
__device__ inline float2 unp(unsigned u) {
    union { unsigned u; h2_t h; } x; x.u = u;
    return make_float2((float)x.h.x, (float)x.h.y);
}
__device__ inline unsigned short f16r(float a) {
    union { _Float16 h; unsigned short s; } x; x.h = (_Float16)a; return x.s;
}

// ===========================================================================
// CSR build. Combined bucket space [0,2N): [0,N)=e2n (payload = f16 feat row),
// [N,2N)=n2n (payload = ushort src id).
// ===========================================================================
__global__ __launch_bounds__(256) void hist_kernel(
    const int* __restrict__ e2n_dst, const int* __restrict__ edge_dst,
    int* __restrict__ cnt, int E)
{
    int e = blockIdx.x * 256 + threadIdx.x;
    if (e >= E) return;
    atomicAdd(&cnt[e2n_dst[e]], 1);
    atomicAdd(&cnt[NN + edge_dst[e]], 1);
}

__global__ __launch_bounds__(256) void scan_reduce(
    const int* __restrict__ cnt, int* __restrict__ partial, int TOT)
{
    __shared__ int s[256];
    const int tid = threadIdx.x;
    const int i = blockIdx.x * 256 + tid;
    s[tid] = (i < TOT) ? cnt[i] : 0;
    __syncthreads();
    for (int o = 128; o > 0; o >>= 1) {
        if (tid < o) s[tid] += s[tid + o];
        __syncthreads();
    }
    if (tid == 0) partial[blockIdx.x] = s[0];
}

__global__ __launch_bounds__(1024) void scan_partials(int* partial, int NB)
{
    __shared__ int s[1024];
    const int tid = threadIdx.x;
    const int v = (tid < NB) ? partial[tid] : 0;
    s[tid] = v;
    __syncthreads();
    for (int o = 1; o < 1024; o <<= 1) {
        int t = (tid >= o) ? s[tid - o] : 0;
        __syncthreads();
        s[tid] += t;
        __syncthreads();
    }
    if (tid < NB) partial[tid] = s[tid] - v;
}

__global__ __launch_bounds__(256) void scan_final(
    const int* __restrict__ cnt, const int* __restrict__ partial,
    int* __restrict__ rowptr, int* __restrict__ cursor, int TOT)
{
    __shared__ int s[256];
    const int tid = threadIdx.x;
    const int i = blockIdx.x * 256 + tid;
    const int v = (i < TOT) ? cnt[i] : 0;
    s[tid] = v;
    __syncthreads();
    for (int o = 1; o < 256; o <<= 1) {
        int t = (tid >= o) ? s[tid - o] : 0;
        __syncthreads();
        s[tid] += t;
        __syncthreads();
    }
    const int excl = s[tid] - v + partial[blockIdx.x];
    if (i < TOT) { rowptr[i] = excl; cursor[i] = excl; }
    if (i == TOT - 1) rowptr[TOT] = excl + v;
}

// fill_e2n: coalesced read edge_feat, pack f16, scatter 32 B to CSR slot.
__global__ __launch_bounds__(256) void fill_e2n(
    const float* __restrict__ edge_feat, const int* __restrict__ e2n_dst,
    int* __restrict__ cursor, uint4* __restrict__ pfeat, int E)
{
    int e = blockIdx.x * 256 + threadIdx.x;
    if (e >= E) return;
    const float4* ef = reinterpret_cast<const float4*>(edge_feat + (size_t)e * EF);
    float4 a = ef[0], b = ef[1], c = ef[2], d = ef[3];
    uint4 u0, u1;
    u0.x = packh2(a.x, a.y); u0.y = packh2(a.z, a.w);
    u0.z = packh2(b.x, b.y); u0.w = packh2(b.z, b.w);
    u1.x = packh2(c.x, c.y); u1.y = packh2(c.z, c.w);
    u1.z = packh2(d.x, d.y); u1.w = packh2(d.z, d.w);
    int p = atomicAdd(&cursor[e2n_dst[e]], 1);
    pfeat[(size_t)p * 2]     = u0;
    pfeat[(size_t)p * 2 + 1] = u1;
}

// fill_n2n: scatter ushort src id to n2n CSR slot.
__global__ __launch_bounds__(256) void fill_n2n(
    const int* __restrict__ edge_src, const int* __restrict__ edge_dst,
    int* __restrict__ cursor, unsigned short* __restrict__ idxn, int E)
{
    int e = blockIdx.x * 256 + threadIdx.x;
    if (e >= E) return;
    int q = atomicAdd(&cursor[NN + edge_dst[e]], 1);
    idxn[q - E] = (unsigned short)edge_src[e];
}

// ===========================================================================
// e2n_dense: pool[n] = sum over CSR range of relu(feat @ W_e2l), f16 dot2.
// One wave per node; lane owns dims (lane, lane+64); W in registers as h2.
// ===========================================================================
__global__ __launch_bounds__(256) void e2n_dense(
    const uint4* __restrict__ pfeat, const float* __restrict__ W,
    const int* __restrict__ rowptr, float* __restrict__ pool, int N)
{
    const int lane = threadIdx.x & 63;
    const int n = blockIdx.x * 4 + (threadIdx.x >> 6);
    if (n >= N) return;

    h2_t w0[8], w1[8];
#pragma unroll
    for (int j = 0; j < 8; ++j) {
        w0[j].x = (_Float16)W[(2 * j)     * LATENT + lane];
        w0[j].y = (_Float16)W[(2 * j + 1) * LATENT + lane];
        w1[j].x = (_Float16)W[(2 * j)     * LATENT + lane + 64];
        w1[j].y = (_Float16)W[(2 * j + 1) * LATENT + lane + 64];
    }

    const int beg = rowptr[n], end = rowptr[n + 1];
    float a0 = 0.f, a1 = 0.f;
#pragma unroll 2
    for (int p = beg; p < end; ++p) {
        const uint4 u0 = pfeat[(size_t)p * 2];
        const uint4 u1 = pfeat[(size_t)p * 2 + 1];
        float x0, x1;
        x0 = fdot2f(as_h2(u0.x), w0[0], 0.f);
        x1 = fdot2f(as_h2(u0.x), w1[0], 0.f);
        x0 = fdot2f(as_h2(u0.y), w0[1], x0);
        x1 = fdot2f(as_h2(u0.y), w1[1], x1);
        x0 = fdot2f(as_h2(u0.z), w0[2], x0);
        x1 = fdot2f(as_h2(u0.z), w1[2], x1);
        x0 = fdot2f(as_h2(u0.w), w0[3], x0);
        x1 = fdot2f(as_h2(u0.w), w1[3], x1);
        x0 = fdot2f(as_h2(u1.x), w0[4], x0);
        x1 = fdot2f(as_h2(u1.x), w1[4], x1);
        x0 = fdot2f(as_h2(u1.y), w0[5], x0);
        x1 = fdot2f(as_h2(u1.y), w1[5], x1);
        x0 = fdot2f(as_h2(u1.z), w0[6], x0);
        x1 = fdot2f(as_h2(u1.z), w1[6], x1);
        x0 = fdot2f(as_h2(u1.w), w0[7], x0);
        x1 = fdot2f(as_h2(u1.w), w1[7], x1);
        a0 += fmaxf(x0, 0.f);
        a1 += fmaxf(x1, 0.f);
    }
    pool[(size_t)n * LATENT + lane]      = a0;
    pool[(size_t)n * LATENT + lane + 64] = a1;
}

// ===========================================================================
// static_gemm: static_msg = pool @ W0; h = relu(static_msg). 16-row tiles.
// ===========================================================================
__global__ __launch_bounds__(256) void static_gemm(
    const float* __restrict__ pool, const float* __restrict__ W0,
    float* __restrict__ static_msg, float* __restrict__ h, int N)
{
    __shared__ float sA[16][LATENT];
    const int tid = threadIdx.x;
    const int d = tid & 127, half = tid >> 7;
    const int row0 = blockIdx.x * 16;

    const float4* src = reinterpret_cast<const float4*>(pool + (size_t)row0 * LATENT);
    float4* dst = reinterpret_cast<float4*>(&sA[0][0]);
    dst[tid] = src[tid];
    dst[tid + 256] = src[tid + 256];
    __syncthreads();

    float acc[8];
#pragma unroll
    for (int r = 0; r < 8; ++r) acc[r] = 0.f;

#pragma unroll 4
    for (int k = 0; k < LATENT; ++k) {
        const float w = W0[k * LATENT + d];
#pragma unroll
        for (int r = 0; r < 8; ++r)
            acc[r] = fmaf(sA[half * 8 + r][k], w, acc[r]);
    }
#pragma unroll
    for (int r = 0; r < 8; ++r) {
        const size_t o = (size_t)(row0 + half * 8 + r) * LATENT + d;
        static_msg[o] = acc[r];
        h[o] = fmaxf(acc[r], 0.f);
    }
}

// ===========================================================================
// layer_gemm: base = static_msg + h @ W1 ;  g = f16(h @ W2). 16-row tiles.
// ===========================================================================
__global__ __launch_bounds__(256) void layer_gemm(
    const float* __restrict__ h, const float* __restrict__ static_msg,
    const float* __restrict__ W1, const float* __restrict__ W2,
    float* __restrict__ base, unsigned short* __restrict__ g, int N)
{
    __shared__ float sH[16][LATENT];
    const int tid = threadIdx.x;
    const int d = tid & 127, half = tid >> 7;
    const int row0 = blockIdx.x * 16;

    const float4* src = reinterpret_cast<const float4*>(h + (size_t)row0 * LATENT);
    float4* dst = reinterpret_cast<float4*>(&sH[0][0]);
    dst[tid] = src[tid];
    dst[tid + 256] = src[tid + 256];
    __syncthreads();

    float acc1[8], acc2[8];
#pragma unroll
    for (int r = 0; r < 8; ++r) { acc1[r] = 0.f; acc2[r] = 0.f; }

#pragma unroll 4
    for (int k = 0; k < LATENT; ++k) {
        const float w1 = W1[k * LATENT + d];
        const float w2 = W2[k * LATENT + d];
#pragma unroll
        for (int r = 0; r < 8; ++r) {
            const float a = sH[half * 8 + r][k];
            acc1[r] = fmaf(a, w1, acc1[r]);
            acc2[r] = fmaf(a, w2, acc2[r]);
        }
    }
#pragma unroll
    for (int r = 0; r < 8; ++r) {
        const size_t o = (size_t)(row0 + half * 8 + r) * LATENT + d;
        base[o] = static_msg[o] + acc1[r];
        g[o] = f16r(acc2[r]);
    }
}

// ===========================================================================
// n2n_apply: out[n] = relu(base[n] + sum over edges of g[src]) (g f16).
// One wave per node; half-wave handles alternating edges, 4-edge batches
// (8 gather loads in flight per wave). idxn is ushort.
// ===========================================================================
__global__ __launch_bounds__(256) void n2n_apply(
    const unsigned short* __restrict__ g, const float* __restrict__ base,
    const int* __restrict__ rowptr, const unsigned short* __restrict__ idxn,
    float* __restrict__ out, int N, int E)
{
    const int lane = threadIdx.x & 63;
    const int n = blockIdx.x * 4 + (threadIdx.x >> 6);
    if (n >= N) return;
    const int sub = lane >> 5;
    const int s4 = lane & 31;
    const char* gB = reinterpret_cast<const char*>(g);

    const int beg = rowptr[NN + n] - E;
    const int end = rowptr[NN + n + 1] - E;

    float4 accA = {0.f, 0.f, 0.f, 0.f};
    float4 accB = {0.f, 0.f, 0.f, 0.f};
    int pos = beg + sub;
    for (; pos + 6 < end; pos += 8) {
        const int s0 = idxn[pos];
        const int s1 = idxn[pos + 2];
        const int s2 = idxn[pos + 4];
        const int s3 = idxn[pos + 6];
        const uint2 u0 = *reinterpret_cast<const uint2*>(gB + (size_t)s0 * 256 + s4 * 8);
        const uint2 u1 = *reinterpret_cast<const uint2*>(gB + (size_t)s1 * 256 + s4 * 8);
        const uint2 u2 = *reinterpret_cast<const uint2*>(gB + (size_t)s2 * 256 + s4 * 8);
        const uint2 u3 = *reinterpret_cast<const uint2*>(gB + (size_t)s3 * 256 + s4 * 8);
        float2 f;
        f = unp(u0.x); accA.x += f.x; accA.y += f.y;
        f = unp(u0.y); accA.z += f.x; accA.w += f.y;
        f = unp(u1.x); accB.x += f.x; accB.y += f.y;
        f = unp(u1.y); accB.z += f.x; accB.w += f.y;
        f = unp(u2.x); accA.x += f.x; accA.y += f.y;
        f = unp(u2.y); accA.z += f.x; accA.w += f.y;
        f = unp(u3.x); accB.x += f.x; accB.y += f.y;
        f = unp(u3.y); accB.z += f.x; accB.w += f.y;
    }
    for (; pos < end; pos += 2) {
        const int s0 = idxn[pos];
        const uint2 u0 = *reinterpret_cast<const uint2*>(gB + (size_t)s0 * 256 + s4 * 8);
        float2 f;
        f = unp(u0.x); accA.x += f.x; accA.y += f.y;
        f = unp(u0.y); accA.z += f.x; accA.w += f.y;
    }
    accA.x += accB.x; accA.y += accB.y; accA.z += accB.z; accA.w += accB.w;

    accA.x += __shfl_xor(accA.x, 32);
    accA.y += __shfl_xor(accA.y, 32);
    accA.z += __shfl_xor(accA.z, 32);
    accA.w += __shfl_xor(accA.w, 32);

    if (sub == 0) {
        const size_t o = (size_t)n * LATENT + s4 * 4;
        const float4 b = *reinterpret_cast<const float4*>(base + o);
        float4 r;
        r.x = fmaxf(b.x + accA.x, 0.f);
        r.y = fmaxf(b.y + accA.y, 0.f);
        r.z = fmaxf(b.z + accA.z, 0.f);
        r.w = fmaxf(b.w + accA.w, 0.f);
        *reinterpret_cast<float4*>(out + o) = r;
    }
}

// ===========================================================================
extern "C" void kernel_launch(void* const* d_in, const int* in_sizes, int n_in,
                              void* d_out, int out_size, void* d_ws, size_t ws_size,
                              hipStream_t stream)
{
    const float* edge_feat = (const float*)d_in[0];
    const float* W_e2l     = (const float*)d_in[1];
    const float* W0        = (const float*)d_in[2];
    const float* W1_1      = (const float*)d_in[3];
    const float* W2_1      = (const float*)d_in[4];
    const float* W1_2      = (const float*)d_in[5];
    const float* W2_2      = (const float*)d_in[6];
    const float* W1_3      = (const float*)d_in[7];
    const float* W2_3      = (const float*)d_in[8];
    const int* e2n_dst     = (const int*)d_in[9];
    const int* edge_src    = (const int*)d_in[10];
    const int* edge_dst    = (const int*)d_in[11];

    const int E   = in_sizes[9];          // 1,600,000
    const int N   = NN;                   // 50,000
    const int TOT = 2 * N;
    const int NB  = (TOT + 255) / 256;

    const size_t matBytes = (size_t)N * LATENT * sizeof(float);  // 25.6 MB
    char* ws = (char*)d_ws;
    size_t off = 0;
    auto alloc = [&](size_t bytes) {
        void* p = ws + off;
        off = (off + bytes + 255) & ~(size_t)255;
        return p;
    };
    uint4* pfeat      = (uint4*)alloc((size_t)E * 32);                   // 51.2 MB
    float* h          = (float*)alloc(matBytes);
    float* static_msg = (float*)alloc(matBytes);
    float* pool       = (float*)alloc(matBytes);                         // = base
    unsigned short* g = (unsigned short*)alloc((size_t)N * LATENT * 2);  // 12.8 MB
    unsigned short* idxn = (unsigned short*)alloc((size_t)E * 2);        // 3.2 MB
    int* cnt          = (int*)alloc((size_t)TOT * sizeof(int));
    int* rowptr       = (int*)alloc((size_t)(TOT + 1) * sizeof(int));
    int* cursor       = (int*)alloc((size_t)TOT * sizeof(int));
    int* partial      = (int*)alloc((size_t)(NB + 1) * sizeof(int));
    float* base       = pool;   // pool is dead after static_gemm
    float* out        = (float*)d_out;

    const int egrid = (E + 255) / 256;

    // ---- CSR build ----
    hipMemsetAsync(cnt, 0, (size_t)TOT * sizeof(int), stream);
    hist_kernel<<<egrid, 256, 0, stream>>>(e2n_dst, edge_dst, cnt, E);
    scan_reduce<<<NB, 256, 0, stream>>>(cnt, partial, TOT);
    scan_partials<<<1, 1024, 0, stream>>>(partial, NB);
    scan_final<<<NB, 256, 0, stream>>>(cnt, partial, rowptr, cursor, TOT);
    fill_e2n<<<egrid, 256, 0, stream>>>(edge_feat, e2n_dst, cursor, pfeat, E);
    fill_n2n<<<egrid, 256, 0, stream>>>(edge_src, edge_dst, cursor, idxn, E);

    // ---- e2n pooling (dense, contiguous, f16 dot2) ----
    e2n_dense<<<(N + 3) / 4, 256, 0, stream>>>(pfeat, W_e2l, rowptr, pool, N);

    // ---- static message + first h ----
    static_gemm<<<N / 16, 256, 0, stream>>>(pool, W0, static_msg, h, N);

    // ---- 3 message-passing layers ----
    const float* Ws1[3] = {W1_1, W1_2, W1_3};
    const float* Ws2[3] = {W2_1, W2_2, W2_3};
    for (int l = 0; l < 3; ++l) {
        layer_gemm<<<N / 16, 256, 0, stream>>>(h, static_msg, Ws1[l], Ws2[l],
                                               base, g, N);
        float* hout = (l == 2) ? out : h;
        n2n_apply<<<(N + 3) / 4, 256, 0, stream>>>(g, base, rowptr, idxn,
                                                   hout, N, E);
    }
}